// Round 5
// baseline (461.941 us; speedup 1.0000x reference)
//
#include <hip/hip_runtime.h>
#include <hip/hip_bf16.h>
#include <math.h>

#define NTOK 100352          // 32*56*56
typedef __attribute__((ext_vector_type(8))) short short8_t;
typedef __attribute__((ext_vector_type(4))) float f32x4;

union I4S8 { int4 i; short h[8]; short8_t v; };

__device__ __forceinline__ short f2bf(float f) {
    union { float f; unsigned u; } x; x.f = f;
    unsigned r = x.u + 0x7FFFu + ((x.u >> 16) & 1u);
    return (short)(r >> 16);
}
__device__ __forceinline__ float bf2f(short s) {
    union { unsigned u; float f; } x; x.u = ((unsigned)(unsigned short)s) << 16;
    return x.f;
}
__device__ __forceinline__ unsigned pk2(float a, float b) {
    return ((unsigned)(unsigned short)f2bf(a)) | (((unsigned)(unsigned short)f2bf(b)) << 16);
}
// exact-GELU via A&S 7.1.26 erf approx (|err| <= 1.5e-7), ~12 VALU ops
__device__ __forceinline__ float gelu(float x) {
    float z = x * 0.70710678118654752f;
    float az = fabsf(z);
    float t = 1.0f / (1.0f + 0.3275911f * az);
    float poly = t * (0.254829592f + t * (-0.284496736f + t * (1.421413741f +
                 t * (-1.453152027f + t * 1.061405429f))));
    float e = 1.0f - poly * __expf(-az * az);
    float erfv = (z < 0.f) ? -e : e;
    return 0.5f * x * (1.0f + erfv);
}

// ---------------- weight prep: f32 [K][N] -> bf16 [N][K] ----------------
__global__ void prep_weights(const float* __restrict__ qkv_w, const float* __restrict__ proj_w,
                             const float* __restrict__ fc1_w, const float* __restrict__ fc2_w,
                             short* __restrict__ wt) {
    int idx = blockIdx.x * 256 + threadIdx.x;
    const float* src; int K, N, base;
    if (idx < 49152)       { src = qkv_w;  K = 128; N = 384; base = 0; }
    else if (idx < 65536)  { src = proj_w; K = 128; N = 128; base = 49152; }
    else if (idx < 131072) { src = fc1_w;  K = 128; N = 512; base = 65536; }
    else                   { src = fc2_w;  K = 512; N = 128; base = 131072; }
    int local = idx - base;
    int n = local / K, k = local - n * K;
    wt[idx] = f2bf(src[k * N + n]);
}

// ---------------- LayerNorm (f32 in) -> bf16 out ----------------
__global__ __launch_bounds__(256) void ln_kernel(const float* __restrict__ in,
                                                 const float* __restrict__ g,
                                                 const float* __restrict__ b,
                                                 short* __restrict__ out) {
    int token = blockIdx.x * 4 + (threadIdx.x >> 6);
    int lane = threadIdx.x & 63;
    const float2 v = *reinterpret_cast<const float2*>(in + (size_t)token * 128 + lane * 2);
    float s = v.x + v.y;
    float sq = v.x * v.x + v.y * v.y;
    #pragma unroll
    for (int m = 32; m >= 1; m >>= 1) {
        s  += __shfl_xor(s, m);
        sq += __shfl_xor(sq, m);
    }
    float mean = s * (1.0f / 128.0f);
    float var = sq * (1.0f / 128.0f) - mean * mean;
    float rstd = rsqrtf(var + 1e-5f);
    float2 gg = *reinterpret_cast<const float2*>(g + lane * 2);
    float2 bb = *reinterpret_cast<const float2*>(b + lane * 2);
    float o0 = (v.x - mean) * rstd * gg.x + bb.x;
    float o1 = (v.y - mean) * rstd * gg.y + bb.y;
    unsigned pack = ((unsigned)(unsigned short)f2bf(o0)) |
                    (((unsigned)(unsigned short)f2bf(o1)) << 16);
    *reinterpret_cast<unsigned*>(out + (size_t)token * 128 + lane * 2) = pack;
}

// ---------------- streaming GEMM, K=128, weight-stationary in registers -----------
// grid (M/(64*IT), N/64). Block = 4 waves, all waves share col-group c0 = by*64.
// Wave w, iter it -> 16-token tile at m0 + (it*4+w)*16. NO LDS, NO BARRIERS.
// D layout (mfma(bfr,af)): lane(r,g) holds C[token=tile+r][c0+nt*16+g*4+j].
// EPI 0: pack bf16 -> outb. EPI 1: +bias +residual -> f32 outf (proj->xres).
template<int EPI, int IT>
__global__ __launch_bounds__(256, 4) void sgemm(const short* __restrict__ A,
                                                const short* __restrict__ WT,
                                                const float* __restrict__ bias,
                                                const float* __restrict__ resid,
                                                short* __restrict__ outb,
                                                float* __restrict__ outf,
                                                int N) {
    const int tid = threadIdx.x;
    const int w = tid >> 6, lane = tid & 63;
    const int r = lane & 15, g = lane >> 4;
    const int c0 = blockIdx.y * 64;
    const int m0 = blockIdx.x * (64 * IT);

    // weight panel: 64 cols x K=128 in registers (16 x short8 = 64 VGPR)
    short8_t bfr[4][4];
    #pragma unroll
    for (int nt = 0; nt < 4; ++nt)
        #pragma unroll
        for (int kf = 0; kf < 4; ++kf)
            bfr[nt][kf] = *reinterpret_cast<const short8_t*>(
                WT + (size_t)(c0 + nt * 16 + r) * 128 + kf * 32 + g * 8);

    #pragma unroll 2
    for (int it = 0; it < IT; ++it) {
        const int mrow = m0 + (it * 4 + w) * 16;
        short8_t af[4];
        #pragma unroll
        for (int kf = 0; kf < 4; ++kf)
            af[kf] = *reinterpret_cast<const short8_t*>(
                A + (size_t)(mrow + r) * 128 + kf * 32 + g * 8);
        f32x4 acc[4];
        #pragma unroll
        for (int nt = 0; nt < 4; ++nt) acc[nt] = (f32x4){0.f, 0.f, 0.f, 0.f};
        #pragma unroll
        for (int kf = 0; kf < 4; ++kf)
            #pragma unroll
            for (int nt = 0; nt < 4; ++nt)
                acc[nt] = __builtin_amdgcn_mfma_f32_16x16x32_bf16(bfr[nt][kf], af[kf], acc[nt], 0, 0, 0);

        const int row = mrow + r;
        if (EPI == 0) {
            #pragma unroll
            for (int nt = 0; nt < 4; ++nt) {
                int col = c0 + nt * 16 + g * 4;
                uint2 p;
                p.x = pk2(acc[nt][0], acc[nt][1]);
                p.y = pk2(acc[nt][2], acc[nt][3]);
                *reinterpret_cast<uint2*>(&outb[(size_t)row * N + col]) = p;
            }
        } else {
            #pragma unroll
            for (int nt = 0; nt < 4; ++nt) {
                int col = c0 + nt * 16 + g * 4;
                f32x4 b4 = *reinterpret_cast<const f32x4*>(&bias[col]);
                f32x4 x4 = *reinterpret_cast<const f32x4*>(&resid[(size_t)row * 128 + col]);
                f32x4 v;
                #pragma unroll
                for (int j = 0; j < 4; ++j) v[j] = acc[nt][j] + b4[j] + x4[j];
                *reinterpret_cast<f32x4*>(&outf[(size_t)row * 128 + col]) = v;
            }
        }
    }
}

// ---------------- fused MLP: fc1 + GELU + fc2 + bias + residual ----------------
// 64-token tile; hidden processed in 2 chunks of 256 cols; LDS 32 KB -> 4-5 blocks/CU.
// fc2 accumulators persist across chunks.
__global__ __launch_bounds__(256, 4) void mlp_kernel(const short* __restrict__ Y,
                                                     const short* __restrict__ W1T,   // [512][128]
                                                     const float* __restrict__ b1,
                                                     const short* __restrict__ W2T,   // [128][512]
                                                     const float* __restrict__ b2,
                                                     const float* __restrict__ xres,
                                                     float* __restrict__ out) {
    __shared__ short hid[64 * 256];   // 32 KB, row stride 512 B, XOR-swizzled 16B segs
    const int m0 = blockIdx.x * 64;
    const int tid = threadIdx.x;
    const int w = tid >> 6, lane = tid & 63;
    const int r = lane & 15, g = lane >> 4;

    f32x4 acc2[4][2];
    #pragma unroll
    for (int tt = 0; tt < 4; ++tt)
        #pragma unroll
        for (int o = 0; o < 2; ++o) acc2[tt][o] = (f32x4){0.f, 0.f, 0.f, 0.f};

    #pragma unroll
    for (int c = 0; c < 2; ++c) {
        // ---- fc1: wave w -> hidden cols c*256 + w*64 .. +63, per-mf to cap VGPR ----
        #pragma unroll
        for (int mf = 0; mf < 4; ++mf) {
            f32x4 acc[4];
            #pragma unroll
            for (int nt = 0; nt < 4; ++nt) acc[nt] = (f32x4){0.f, 0.f, 0.f, 0.f};
            #pragma unroll
            for (int kf = 0; kf < 4; ++kf) {
                short8_t afk = *reinterpret_cast<const short8_t*>(
                    Y + (size_t)(m0 + mf * 16 + r) * 128 + kf * 32 + g * 8);
                #pragma unroll
                for (int nt = 0; nt < 4; ++nt) {
                    short8_t bf1 = *reinterpret_cast<const short8_t*>(
                        W1T + (size_t)(c * 256 + w * 64 + nt * 16 + r) * 128 + kf * 32 + g * 8);
                    acc[nt] = __builtin_amdgcn_mfma_f32_16x16x32_bf16(bf1, afk, acc[nt], 0, 0, 0);
                }
            }
            int row = mf * 16 + r;
            #pragma unroll
            for (int nt = 0; nt < 4; ++nt) {
                int lc = w * 64 + nt * 16 + g * 4;          // local col 0..255
                int col = c * 256 + lc;
                f32x4 b4 = *reinterpret_cast<const f32x4*>(&b1[col]);
                float h0 = gelu(acc[nt][0] + b4[0]);
                float h1 = gelu(acc[nt][1] + b4[1]);
                float h2 = gelu(acc[nt][2] + b4[2]);
                float h3 = gelu(acc[nt][3] + b4[3]);
                int seg = lc >> 3;                           // 0..31
                int half = (lc >> 2) & 1;
                int sw = (seg & 24) | ((seg ^ row) & 7);
                uint2 p; p.x = pk2(h0, h1); p.y = pk2(h2, h3);
                *reinterpret_cast<uint2*>((char*)hid + row * 512 + sw * 16 + half * 8) = p;
            }
        }
        __syncthreads();
        // ---- fc2 partial over this chunk's K=256 ----
        #pragma unroll
        for (int kq = 0; kq < 8; ++kq) {
            short8_t bf2[2], hf[4];
            #pragma unroll
            for (int o = 0; o < 2; ++o)
                bf2[o] = *reinterpret_cast<const short8_t*>(
                    W2T + (size_t)(w * 32 + o * 16 + r) * 512 + c * 256 + kq * 32 + g * 8);
            #pragma unroll
            for (int tt = 0; tt < 4; ++tt) {
                int row = tt * 16 + r;
                int seg = kq * 4 + g;
                int sw = (seg & 24) | ((seg ^ row) & 7);
                hf[tt] = *reinterpret_cast<const short8_t*>((char*)hid + row * 512 + sw * 16);
            }
            #pragma unroll
            for (int tt = 0; tt < 4; ++tt)
                #pragma unroll
                for (int o = 0; o < 2; ++o)
                    acc2[tt][o] = __builtin_amdgcn_mfma_f32_16x16x32_bf16(bf2[o], hf[tt], acc2[tt][o], 0, 0, 0);
        }
        __syncthreads();
    }

    #pragma unroll
    for (int tt = 0; tt < 4; ++tt) {
        int row = m0 + tt * 16 + r;
        #pragma unroll
        for (int o = 0; o < 2; ++o) {
            int col = w * 32 + o * 16 + g * 4;
            f32x4 b4 = *reinterpret_cast<const f32x4*>(&b2[col]);
            f32x4 x4 = *reinterpret_cast<const f32x4*>(&xres[(size_t)row * 128 + col]);
            f32x4 v;
            #pragma unroll
            for (int j = 0; j < 4; ++j) v[j] = acc2[tt][o][j] + b4[j] + x4[j];
            *reinterpret_cast<f32x4*>(&out[(size_t)row * 128 + col]) = v;
        }
    }
}

// ---------------- fused window attention + LEPE (wave-parallel softmax) ----------------
// grid (896, 2, 2): x = window (b*28 + w), y = head, z = type (0: 56x2, 1: 2x56)
__global__ __launch_bounds__(256) void attn_kernel(const short* __restrict__ qkv,
                                                   const float* __restrict__ cw0,
                                                   const float* __restrict__ cb0,
                                                   const float* __restrict__ cw1,
                                                   const float* __restrict__ cb1,
                                                   short* __restrict__ attout) {
    __shared__ short P[112][120];   // normalized probs, bf16
    __shared__ short vT[32][120];   // V transposed: vT[d][tok]

    const int win = blockIdx.x;
    const int head = blockIdx.y;
    const int type = blockIdx.z;
    const int b = win / 28;
    const int wdx = win - b * 28;
    const int tid = threadIdx.x;
    const int wv = tid >> 6, lane = tid & 63;
    const int r = lane & 15, g = lane >> 4;
    const int chb = type * 64 + head * 32;
    const float* cw = type ? cw1 : cw0;
    const float* cb = type ? cb1 : cb0;

    auto rowof = [&](int t) -> int {
        int l;
        if (type == 0) { int hs = t >> 1, wsp = t & 1; l = hs * 56 + wdx * 2 + wsp; }
        else           { int hs = (t >= 56) ? 1 : 0, wsp = t - hs * 56; l = (wdx * 2 + hs) * 56 + wsp; }
        return b * 3136 + l;
    };

    // stage V transposed: vT[d][tok]
    for (int i = tid; i < 448; i += 256) {
        int tt = i >> 2, seg = i & 3;
        int roww = rowof(tt);
        I4S8 u; u.i = *reinterpret_cast<const int4*>(qkv + (size_t)roww * 384 + 256 + chb + seg * 8);
        #pragma unroll
        for (int j = 0; j < 8; ++j) vT[seg * 8 + j][tt] = u.h[j];
    }

    // K-frags (B-operand) in registers, shared across this wave's m-tiles
    short8_t kf[7];
    #pragma unroll
    for (int nt = 0; nt < 7; ++nt) {
        int roww = rowof(nt * 16 + r);
        kf[nt] = *reinterpret_cast<const short8_t*>(qkv + (size_t)roww * 384 + 128 + chb + g * 8);
    }

    // QK^T into registers: sa[t][nt], t indexes this wave's m-tiles {wv, wv+4}
    f32x4 sa[2][7];
    #pragma unroll
    for (int t = 0; t < 2; ++t)
        #pragma unroll
        for (int nt = 0; nt < 7; ++nt)
            sa[t][nt] = (f32x4){0.f, 0.f, 0.f, 0.f};

    #pragma unroll
    for (int t = 0; t < 2; ++t) {
        int mt = wv + 4 * t;
        if (mt < 7) {
            int roww = rowof(mt * 16 + r);
            short8_t af = *reinterpret_cast<const short8_t*>(qkv + (size_t)roww * 384 + chb + g * 8);
            #pragma unroll
            for (int nt = 0; nt < 7; ++nt)
                sa[t][nt] = __builtin_amdgcn_mfma_f32_16x16x32_bf16(af, kf[nt], sa[t][nt], 0, 0, 0);
        }
    }

    // in-register softmax; rows of frag = g*4+j, cols nt*16+r (16-lane group)
    const float scale = 0.17677669529663687f; // 1/sqrt(32)
    #pragma unroll
    for (int t = 0; t < 2; ++t) {
        int mt = wv + 4 * t;
        if (mt < 7) {
            #pragma unroll
            for (int j = 0; j < 4; ++j) {
                float sv[7];
                float mx = -1e30f;
                #pragma unroll
                for (int nt = 0; nt < 7; ++nt) { sv[nt] = sa[t][nt][j] * scale; mx = fmaxf(mx, sv[nt]); }
                #pragma unroll
                for (int m = 8; m >= 1; m >>= 1) mx = fmaxf(mx, __shfl_xor(mx, m));
                float sum = 0.f;
                #pragma unroll
                for (int nt = 0; nt < 7; ++nt) { sv[nt] = __expf(sv[nt] - mx); sum += sv[nt]; }
                #pragma unroll
                for (int m = 8; m >= 1; m >>= 1) sum += __shfl_xor(sum, m);
                float inv = 1.0f / sum;
                int row = mt * 16 + g * 4 + j;
                #pragma unroll
                for (int nt = 0; nt < 7; ++nt)
                    P[row][nt * 16 + r] = f2bf(sv[nt] * inv);
            }
        }
    }
    __syncthreads();

    // PV + LEPE + store. 14 output frags (7 m-tiles x 2 d-tiles); wave w: w+4t
    #pragma unroll
    for (int t = 0; t < 4; ++t) {
        int idx = wv + 4 * t;
        if (idx < 14) {
            int mt = idx >> 1, nt = idx & 1;
            int m0 = mt * 16, n0 = nt * 16;
            f32x4 acc = {0.f, 0.f, 0.f, 0.f};
            #pragma unroll
            for (int ks = 0; ks < 4; ++ks) {
                short8_t pa, vb;
                if (ks < 3 || g < 2) {
                    int k0 = ks * 32 + g * 8;
                    pa = *reinterpret_cast<const short8_t*>(&P[m0 + r][k0]);
                    vb = *reinterpret_cast<const short8_t*>(&vT[n0 + r][k0]);
                } else {
                    #pragma unroll
                    for (int j = 0; j < 8; ++j) { pa[j] = 0; vb[j] = 0; }
                }
                acc = __builtin_amdgcn_mfma_f32_16x16x32_bf16(pa, vb, acc, 0, 0, 0);
            }
            int d = n0 + r;               // hd index 0..31
            int cl = head * 32 + d;       // depthwise-conv channel 0..63
            float w9[9];
            #pragma unroll
            for (int j = 0; j < 9; ++j) w9[j] = cw[cl * 9 + j];
            float cbias = cb[cl];
            #pragma unroll
            for (int j = 0; j < 4; ++j) {
                int tok = m0 + g * 4 + j;
                float v = acc[j];
                int hs, wsp;
                if (type == 0) { hs = tok >> 1; wsp = tok & 1; }
                else           { hs = (tok >= 56) ? 1 : 0; wsp = tok - hs * 56; }
                float lp = cbias;
                #pragma unroll
                for (int ky = 0; ky < 3; ++ky) {
                    int hh = hs + ky - 1;
                    bool okh = (type == 0) ? (hh >= 0 && hh < 56) : (hh >= 0 && hh < 2);
                    #pragma unroll
                    for (int kx = 0; kx < 3; ++kx) {
                        int wwp = wsp + kx - 1;
                        bool okw = (type == 0) ? (wwp >= 0 && wwp < 2) : (wwp >= 0 && wwp < 56);
                        if (okh && okw) {
                            int tt = (type == 0) ? (hh * 2 + wwp) : (hh * 56 + wwp);
                            lp += w9[ky * 3 + kx] * bf2f(vT[d][tt]);
                        }
                    }
                }
                v += lp;
                int roww = rowof(tok);
                attout[(size_t)roww * 128 + chb + d] = f2bf(v);
            }
        }
    }
}

extern "C" void kernel_launch(void* const* d_in, const int* in_sizes, int n_in,
                              void* d_out, int out_size, void* d_ws, size_t ws_size,
                              hipStream_t stream) {
    const float* x      = (const float*)d_in[0];
    const float* n1g    = (const float*)d_in[1];
    const float* n1b    = (const float*)d_in[2];
    const float* qkv_w  = (const float*)d_in[3];
    const float* proj_w = (const float*)d_in[4];
    const float* proj_b = (const float*)d_in[5];
    const float* cw0    = (const float*)d_in[6];
    const float* cb0    = (const float*)d_in[7];
    const float* cw1    = (const float*)d_in[8];
    const float* cb1    = (const float*)d_in[9];
    const float* n2g    = (const float*)d_in[10];
    const float* n2b    = (const float*)d_in[11];
    const float* fc1_w  = (const float*)d_in[12];
    const float* fc1_b  = (const float*)d_in[13];
    const float* fc2_w  = (const float*)d_in[14];
    const float* fc2_b  = (const float*)d_in[15];
    float* out = (float*)d_out;
    char* ws = (char*)d_ws;

    // workspace layout (bytes)
    short* img   = (short*)(ws + 0);            // [100352][128] bf16; later y2 (LN2 out)
    short* qkv   = (short*)(ws + 25690112);     // [100352][384] bf16
    short* att   = (short*)(ws + 102760448);    // [100352][128] bf16
    float* xres  = (float*)(ws + 128450560);    // [100352][128] f32
    short* wT    = (short*)(ws + 179830784);    // all weights bf16 [N][K]
    short* wqkvT  = wT;
    short* wprojT = wT + 49152;
    short* wfc1T  = wT + 65536;
    short* wfc2T  = wT + 131072;
    short* y2     = img;   // LN2 output aliases img (dead after qkv GEMM)

    prep_weights<<<768, 256, 0, stream>>>(qkv_w, proj_w, fc1_w, fc2_w, wT);
    ln_kernel<<<25088, 256, 0, stream>>>(x, n1g, n1b, img);
    sgemm<0, 8><<<dim3(196, 6), 256, 0, stream>>>(img, wqkvT, nullptr, nullptr, qkv, nullptr, 384);
    attn_kernel<<<dim3(896, 2, 2), 256, 0, stream>>>(qkv, cw0, cb0, cw1, cb1, att);
    sgemm<1, 4><<<dim3(392, 2), 256, 0, stream>>>(att, wprojT, proj_b, x, nullptr, xres, 128);
    ln_kernel<<<25088, 256, 0, stream>>>(xres, n2g, n2b, y2);
    mlp_kernel<<<1568, 256, 0, stream>>>(y2, wfc1T, fc1_b, wfc2T, fc2_b, xres, out);
}

// Round 6
// 436.373 us; speedup vs baseline: 1.0586x; 1.0586x over previous
//
#include <hip/hip_runtime.h>
#include <hip/hip_bf16.h>
#include <math.h>

#define NTOK 100352          // 32*56*56
typedef __attribute__((ext_vector_type(8))) short short8_t;
typedef __attribute__((ext_vector_type(4))) float f32x4;

union I4S8 { int4 i; short h[8]; short8_t v; };

__device__ __forceinline__ short f2bf(float f) {
    union { float f; unsigned u; } x; x.f = f;
    unsigned r = x.u + 0x7FFFu + ((x.u >> 16) & 1u);
    return (short)(r >> 16);
}
__device__ __forceinline__ float bf2f(short s) {
    union { unsigned u; float f; } x; x.u = ((unsigned)(unsigned short)s) << 16;
    return x.f;
}
__device__ __forceinline__ unsigned pk2(float a, float b) {
    return ((unsigned)(unsigned short)f2bf(a)) | (((unsigned)(unsigned short)f2bf(b)) << 16);
}
// exact-GELU via A&S 7.1.26 erf approx (|err| <= 1.5e-7), ~12 VALU ops
__device__ __forceinline__ float gelu(float x) {
    float z = x * 0.70710678118654752f;
    float az = fabsf(z);
    float t = 1.0f / (1.0f + 0.3275911f * az);
    float poly = t * (0.254829592f + t * (-0.284496736f + t * (1.421413741f +
                 t * (-1.453152027f + t * 1.061405429f))));
    float e = 1.0f - poly * __expf(-az * az);
    float erfv = (z < 0.f) ? -e : e;
    return 0.5f * x * (1.0f + erfv);
}

// async global->LDS, 16B per lane, wave-uniform LDS base + lane*16
#define GLDS16(gsrc, ldst) __builtin_amdgcn_global_load_lds( \
    (const __attribute__((address_space(1))) unsigned int*)(gsrc), \
    (__attribute__((address_space(3))) unsigned int*)(ldst), 16, 0, 0)

// ---------------- weight prep: f32 [K][N] -> bf16 [N][K] ----------------
__global__ void prep_weights(const float* __restrict__ qkv_w, const float* __restrict__ proj_w,
                             const float* __restrict__ fc1_w, const float* __restrict__ fc2_w,
                             short* __restrict__ wt) {
    int idx = blockIdx.x * 256 + threadIdx.x;
    const float* src; int K, N, base;
    if (idx < 49152)       { src = qkv_w;  K = 128; N = 384; base = 0; }
    else if (idx < 65536)  { src = proj_w; K = 128; N = 128; base = 49152; }
    else if (idx < 131072) { src = fc1_w;  K = 128; N = 512; base = 65536; }
    else                   { src = fc2_w;  K = 512; N = 128; base = 131072; }
    int local = idx - base;
    int n = local / K, k = local - n * K;
    wt[idx] = f2bf(src[k * N + n]);
}

// ---------------- LayerNorm (f32 in) -> bf16 out ----------------
__global__ __launch_bounds__(256) void ln_kernel(const float* __restrict__ in,
                                                 const float* __restrict__ g,
                                                 const float* __restrict__ b,
                                                 short* __restrict__ out) {
    int token = blockIdx.x * 4 + (threadIdx.x >> 6);
    int lane = threadIdx.x & 63;
    const float2 v = *reinterpret_cast<const float2*>(in + (size_t)token * 128 + lane * 2);
    float s = v.x + v.y;
    float sq = v.x * v.x + v.y * v.y;
    #pragma unroll
    for (int m = 32; m >= 1; m >>= 1) {
        s  += __shfl_xor(s, m);
        sq += __shfl_xor(sq, m);
    }
    float mean = s * (1.0f / 128.0f);
    float var = sq * (1.0f / 128.0f) - mean * mean;
    float rstd = rsqrtf(var + 1e-5f);
    float2 gg = *reinterpret_cast<const float2*>(g + lane * 2);
    float2 bb = *reinterpret_cast<const float2*>(b + lane * 2);
    float o0 = (v.x - mean) * rstd * gg.x + bb.x;
    float o1 = (v.y - mean) * rstd * gg.y + bb.y;
    unsigned pack = ((unsigned)(unsigned short)f2bf(o0)) |
                    (((unsigned)(unsigned short)f2bf(o1)) << 16);
    *reinterpret_cast<unsigned*>(out + (size_t)token * 128 + lane * 2) = pack;
}

// ---------------- qkv GEMM: 128 rows x 64 cols per block, K=128 one-shot ----------
// grid (6, 784): x = col-group (fast-varying -> consecutive blocks share A tile in L2),
// y = row tile. A staged via global_load_lds (coalesced, XOR-swizzled); W panel in
// registers (L2-hot); ONE barrier; packed 8B bf16 stores.
__global__ __launch_bounds__(256) void gemm_qkv(const short* __restrict__ A,
                                                const short* __restrict__ WT,
                                                short* __restrict__ outb) {
    __shared__ short As[128 * 128];   // 32 KB
    const int c0 = blockIdx.x * 64;
    const int m0 = blockIdx.y * 128;
    const int tid = threadIdx.x;
    const int w = tid >> 6, lane = tid & 63;
    const int r = lane & 15, g = lane >> 4;
    const int rr = lane >> 4, ss = lane & 15;

    // stage A rows w*32 .. +31 (8 issues x 4 rows), verified swizzle (round 3/4)
    #pragma unroll
    for (int t = 0; t < 8; ++t) {
        int row = w * 32 + t * 4 + rr;
        int sseg = (ss & 8) | ((ss ^ row) & 7);
        GLDS16(A + (size_t)(m0 + row) * 128 + sseg * 8, &As[(w * 32 + t * 4) * 128]);
    }
    // weight panel 64 cols x K128 -> 64 VGPR
    short8_t bfr[4][4];
    #pragma unroll
    for (int nt = 0; nt < 4; ++nt)
        #pragma unroll
        for (int kf = 0; kf < 4; ++kf)
            bfr[nt][kf] = *reinterpret_cast<const short8_t*>(
                WT + (size_t)(c0 + nt * 16 + r) * 128 + kf * 32 + g * 8);
    __syncthreads();

    // A frags (both m-frags upfront for MFMA ILP)
    short8_t af[2][4];
    #pragma unroll
    for (int mf = 0; mf < 2; ++mf)
        #pragma unroll
        for (int kf = 0; kf < 4; ++kf) {
            int row = w * 32 + mf * 16 + r;
            int q = kf * 4 + g;
            int seg = (q & 8) | ((q ^ row) & 7);
            af[mf][kf] = *reinterpret_cast<const short8_t*>(&As[row * 128 + seg * 8]);
        }

    f32x4 acc[2][4];
    #pragma unroll
    for (int mf = 0; mf < 2; ++mf)
        #pragma unroll
        for (int nt = 0; nt < 4; ++nt) acc[mf][nt] = (f32x4){0.f, 0.f, 0.f, 0.f};
    #pragma unroll
    for (int kf = 0; kf < 4; ++kf)
        #pragma unroll
        for (int mf = 0; mf < 2; ++mf)
            #pragma unroll
            for (int nt = 0; nt < 4; ++nt)
                acc[mf][nt] = __builtin_amdgcn_mfma_f32_16x16x32_bf16(bfr[nt][kf], af[mf][kf], acc[mf][nt], 0, 0, 0);

    #pragma unroll
    for (int mf = 0; mf < 2; ++mf) {
        int row = m0 + w * 32 + mf * 16 + r;
        #pragma unroll
        for (int nt = 0; nt < 4; ++nt) {
            int col = c0 + nt * 16 + g * 4;
            uint2 p;
            p.x = pk2(acc[mf][nt][0], acc[mf][nt][1]);
            p.y = pk2(acc[mf][nt][2], acc[mf][nt][3]);
            *reinterpret_cast<uint2*>(&outb[(size_t)row * 384 + col]) = p;
        }
    }
}

// ---------------- proj GEMM + bias + residual + LN2, 128 rows x 128 cols -----------
// grid (784). Pre-LN values kept packed bf16 in regs; in-wave shfl row stats.
__global__ __launch_bounds__(256) void gemm_proj(const short* __restrict__ A,
                                                 const short* __restrict__ WT,
                                                 const float* __restrict__ bias,
                                                 const float* __restrict__ resid,
                                                 const float* __restrict__ g2,
                                                 const float* __restrict__ b2,
                                                 short* __restrict__ y2,
                                                 float* __restrict__ xres) {
    __shared__ short As[128 * 128];   // 32 KB
    const int m0 = blockIdx.x * 128;
    const int tid = threadIdx.x;
    const int w = tid >> 6, lane = tid & 63;
    const int r = lane & 15, g = lane >> 4;
    const int rr = lane >> 4, ss = lane & 15;

    #pragma unroll
    for (int t = 0; t < 8; ++t) {
        int row = w * 32 + t * 4 + rr;
        int sseg = (ss & 8) | ((ss ^ row) & 7);
        GLDS16(A + (size_t)(m0 + row) * 128 + sseg * 8, &As[(w * 32 + t * 4) * 128]);
    }
    __syncthreads();

    short8_t af[2][4];
    #pragma unroll
    for (int mf = 0; mf < 2; ++mf)
        #pragma unroll
        for (int kf = 0; kf < 4; ++kf) {
            int row = w * 32 + mf * 16 + r;
            int q = kf * 4 + g;
            int seg = (q & 8) | ((q ^ row) & 7);
            af[mf][kf] = *reinterpret_cast<const short8_t*>(&As[row * 128 + seg * 8]);
        }

    uint2 pk[2][2][4];           // packed pre-LN values [grp][mf][nt]
    float s[2] = {0.f, 0.f}, sq[2] = {0.f, 0.f};   // per mf

    #pragma unroll
    for (int grp = 0; grp < 2; ++grp) {
        short8_t bfr[4][4];
        #pragma unroll
        for (int nt = 0; nt < 4; ++nt)
            #pragma unroll
            for (int kf = 0; kf < 4; ++kf)
                bfr[nt][kf] = *reinterpret_cast<const short8_t*>(
                    WT + (size_t)(grp * 64 + nt * 16 + r) * 128 + kf * 32 + g * 8);
        f32x4 acc[2][4];
        #pragma unroll
        for (int mf = 0; mf < 2; ++mf)
            #pragma unroll
            for (int nt = 0; nt < 4; ++nt) acc[mf][nt] = (f32x4){0.f, 0.f, 0.f, 0.f};
        #pragma unroll
        for (int kf = 0; kf < 4; ++kf)
            #pragma unroll
            for (int mf = 0; mf < 2; ++mf)
                #pragma unroll
                for (int nt = 0; nt < 4; ++nt)
                    acc[mf][nt] = __builtin_amdgcn_mfma_f32_16x16x32_bf16(bfr[nt][kf], af[mf][kf], acc[mf][nt], 0, 0, 0);
        #pragma unroll
        for (int mf = 0; mf < 2; ++mf) {
            int row = m0 + w * 32 + mf * 16 + r;
            #pragma unroll
            for (int nt = 0; nt < 4; ++nt) {
                int col = grp * 64 + nt * 16 + g * 4;
                f32x4 b4 = *reinterpret_cast<const f32x4*>(&bias[col]);
                f32x4 x4 = *reinterpret_cast<const f32x4*>(&resid[(size_t)row * 128 + col]);
                f32x4 v;
                #pragma unroll
                for (int j = 0; j < 4; ++j) {
                    v[j] = acc[mf][nt][j] + b4[j] + x4[j];
                    s[mf] += v[j]; sq[mf] += v[j] * v[j];
                }
                *reinterpret_cast<f32x4*>(&xres[(size_t)row * 128 + col]) = v;
                pk[grp][mf][nt].x = pk2(v[0], v[1]);
                pk[grp][mf][nt].y = pk2(v[2], v[3]);
            }
        }
    }

    #pragma unroll
    for (int mf = 0; mf < 2; ++mf) {
        float ss_ = s[mf], qq = sq[mf];
        ss_ += __shfl_xor(ss_, 16); ss_ += __shfl_xor(ss_, 32);
        qq  += __shfl_xor(qq, 16);  qq  += __shfl_xor(qq, 32);
        float mean = ss_ * (1.0f / 128.0f);
        float var = qq * (1.0f / 128.0f) - mean * mean;
        float rstd = rsqrtf(var + 1e-5f);
        int row = m0 + w * 32 + mf * 16 + r;
        #pragma unroll
        for (int grp = 0; grp < 2; ++grp)
            #pragma unroll
            for (int nt = 0; nt < 4; ++nt) {
                int col = grp * 64 + nt * 16 + g * 4;
                f32x4 g4  = *reinterpret_cast<const f32x4*>(&g2[col]);
                f32x4 bb4 = *reinterpret_cast<const f32x4*>(&b2[col]);
                float v0 = bf2f((short)(pk[grp][mf][nt].x & 0xFFFF));
                float v1 = bf2f((short)(pk[grp][mf][nt].x >> 16));
                float v2 = bf2f((short)(pk[grp][mf][nt].y & 0xFFFF));
                float v3 = bf2f((short)(pk[grp][mf][nt].y >> 16));
                uint2 p;
                p.x = pk2((v0 - mean) * rstd * g4[0] + bb4[0],
                          (v1 - mean) * rstd * g4[1] + bb4[1]);
                p.y = pk2((v2 - mean) * rstd * g4[2] + bb4[2],
                          (v3 - mean) * rstd * g4[3] + bb4[3]);
                *reinterpret_cast<uint2*>(&y2[(size_t)row * 128 + col]) = p;
            }
    }
}

// ---------------- fused MLP: fc1 + GELU + fc2 + bias + residual (round-4 struct) ----
__global__ __launch_bounds__(256) void mlp_kernel(const short* __restrict__ Y,
                                                  const short* __restrict__ W1T,   // [512][128]
                                                  const float* __restrict__ b1,
                                                  const short* __restrict__ W2T,   // [128][512]
                                                  const float* __restrict__ b2,
                                                  const float* __restrict__ xres,
                                                  float* __restrict__ out) {
    __shared__ short hid[64 * 512];   // 64 KB
    const int m0 = blockIdx.x * 64;
    const int tid = threadIdx.x;
    const int w = tid >> 6, lane = tid & 63;
    const int r = lane & 15, g = lane >> 4;

    short8_t af[4][4];
    #pragma unroll
    for (int mf = 0; mf < 4; ++mf)
        #pragma unroll
        for (int kf = 0; kf < 4; ++kf)
            af[mf][kf] = *reinterpret_cast<const short8_t*>(
                &Y[(size_t)(m0 + mf * 16 + r) * 128 + kf * 32 + g * 8]);

    #pragma unroll
    for (int np = 0; np < 2; ++np) {
        f32x4 acc[4][4];
        #pragma unroll
        for (int mf = 0; mf < 4; ++mf)
            #pragma unroll
            for (int nt = 0; nt < 4; ++nt) acc[mf][nt] = (f32x4){0.f, 0.f, 0.f, 0.f};
        #pragma unroll
        for (int kf = 0; kf < 4; ++kf) {
            short8_t bfr[4];
            #pragma unroll
            for (int nt = 0; nt < 4; ++nt) {
                int hc = w * 128 + np * 64 + nt * 16 + r;
                bfr[nt] = *reinterpret_cast<const short8_t*>(&W1T[(size_t)hc * 128 + kf * 32 + g * 8]);
            }
            #pragma unroll
            for (int mf = 0; mf < 4; ++mf)
                #pragma unroll
                for (int nt = 0; nt < 4; ++nt)
                    acc[mf][nt] = __builtin_amdgcn_mfma_f32_16x16x32_bf16(bfr[nt], af[mf][kf], acc[mf][nt], 0, 0, 0);
        }
        #pragma unroll
        for (int mf = 0; mf < 4; ++mf) {
            int row = mf * 16 + r;
            #pragma unroll
            for (int nt = 0; nt < 4; ++nt) {
                int col = w * 128 + np * 64 + nt * 16 + g * 4;
                f32x4 b4 = *reinterpret_cast<const f32x4*>(&b1[col]);
                float h0 = gelu(acc[mf][nt][0] + b4[0]);
                float h1 = gelu(acc[mf][nt][1] + b4[1]);
                float h2 = gelu(acc[mf][nt][2] + b4[2]);
                float h3 = gelu(acc[mf][nt][3] + b4[3]);
                int s16 = col >> 3;
                int half = (col >> 2) & 1;
                int seg = (s16 & 56) | ((s16 ^ row) & 7);
                uint2 p; p.x = pk2(h0, h1); p.y = pk2(h2, h3);
                *reinterpret_cast<uint2*>((char*)hid + row * 1024 + seg * 16 + half * 8) = p;
            }
        }
    }
    __syncthreads();

    f32x4 acc2[4][2];
    #pragma unroll
    for (int tt = 0; tt < 4; ++tt)
        #pragma unroll
        for (int o = 0; o < 2; ++o) acc2[tt][o] = (f32x4){0.f, 0.f, 0.f, 0.f};
    #pragma unroll
    for (int kf = 0; kf < 16; ++kf) {
        const int q = kf * 4 + g;
        short8_t bf2[2], hf[4];
        #pragma unroll
        for (int o = 0; o < 2; ++o) {
            int ocol = w * 32 + o * 16 + r;
            bf2[o] = *reinterpret_cast<const short8_t*>(&W2T[(size_t)ocol * 512 + kf * 32 + g * 8]);
        }
        #pragma unroll
        for (int tt = 0; tt < 4; ++tt) {
            int row = tt * 16 + r;
            int seg = (q & 56) | ((q ^ row) & 7);
            hf[tt] = *reinterpret_cast<const short8_t*>((char*)hid + row * 1024 + seg * 16);
        }
        #pragma unroll
        for (int tt = 0; tt < 4; ++tt)
            #pragma unroll
            for (int o = 0; o < 2; ++o)
                acc2[tt][o] = __builtin_amdgcn_mfma_f32_16x16x32_bf16(bf2[o], hf[tt], acc2[tt][o], 0, 0, 0);
    }
    #pragma unroll
    for (int tt = 0; tt < 4; ++tt) {
        int row = m0 + tt * 16 + r;
        #pragma unroll
        for (int o = 0; o < 2; ++o) {
            int col = w * 32 + o * 16 + g * 4;
            f32x4 b4 = *reinterpret_cast<const f32x4*>(&b2[col]);
            f32x4 x4 = *reinterpret_cast<const f32x4*>(&xres[(size_t)row * 128 + col]);
            f32x4 v;
            #pragma unroll
            for (int j = 0; j < 4; ++j) v[j] = acc2[tt][o][j] + b4[j] + x4[j];
            *reinterpret_cast<f32x4*>(&out[(size_t)row * 128 + col]) = v;
        }
    }
}

// ---------------- fused window attention + LEPE (wave-parallel softmax) ----------------
__global__ __launch_bounds__(256) void attn_kernel(const short* __restrict__ qkv,
                                                   const float* __restrict__ cw0,
                                                   const float* __restrict__ cb0,
                                                   const float* __restrict__ cw1,
                                                   const float* __restrict__ cb1,
                                                   short* __restrict__ attout) {
    __shared__ short P[112][120];   // normalized probs, bf16
    __shared__ short vT[32][120];   // V transposed: vT[d][tok]

    const int win = blockIdx.x;
    const int head = blockIdx.y;
    const int type = blockIdx.z;
    const int b = win / 28;
    const int wdx = win - b * 28;
    const int tid = threadIdx.x;
    const int wv = tid >> 6, lane = tid & 63;
    const int r = lane & 15, g = lane >> 4;
    const int chb = type * 64 + head * 32;
    const float* cw = type ? cw1 : cw0;
    const float* cb = type ? cb1 : cb0;

    auto rowof = [&](int t) -> int {
        int l;
        if (type == 0) { int hs = t >> 1, wsp = t & 1; l = hs * 56 + wdx * 2 + wsp; }
        else           { int hs = (t >= 56) ? 1 : 0, wsp = t - hs * 56; l = (wdx * 2 + hs) * 56 + wsp; }
        return b * 3136 + l;
    };

    for (int i = tid; i < 448; i += 256) {
        int tt = i >> 2, seg = i & 3;
        int roww = rowof(tt);
        I4S8 u; u.i = *reinterpret_cast<const int4*>(qkv + (size_t)roww * 384 + 256 + chb + seg * 8);
        #pragma unroll
        for (int j = 0; j < 8; ++j) vT[seg * 8 + j][tt] = u.h[j];
    }

    short8_t kf[7];
    #pragma unroll
    for (int nt = 0; nt < 7; ++nt) {
        int roww = rowof(nt * 16 + r);
        kf[nt] = *reinterpret_cast<const short8_t*>(qkv + (size_t)roww * 384 + 128 + chb + g * 8);
    }

    f32x4 sa[2][7];
    #pragma unroll
    for (int t = 0; t < 2; ++t)
        #pragma unroll
        for (int nt = 0; nt < 7; ++nt)
            sa[t][nt] = (f32x4){0.f, 0.f, 0.f, 0.f};

    #pragma unroll
    for (int t = 0; t < 2; ++t) {
        int mt = wv + 4 * t;
        if (mt < 7) {
            int roww = rowof(mt * 16 + r);
            short8_t af = *reinterpret_cast<const short8_t*>(qkv + (size_t)roww * 384 + chb + g * 8);
            #pragma unroll
            for (int nt = 0; nt < 7; ++nt)
                sa[t][nt] = __builtin_amdgcn_mfma_f32_16x16x32_bf16(af, kf[nt], sa[t][nt], 0, 0, 0);
        }
    }

    const float scale = 0.17677669529663687f; // 1/sqrt(32)
    #pragma unroll
    for (int t = 0; t < 2; ++t) {
        int mt = wv + 4 * t;
        if (mt < 7) {
            #pragma unroll
            for (int j = 0; j < 4; ++j) {
                float sv[7];
                float mx = -1e30f;
                #pragma unroll
                for (int nt = 0; nt < 7; ++nt) { sv[nt] = sa[t][nt][j] * scale; mx = fmaxf(mx, sv[nt]); }
                #pragma unroll
                for (int m = 8; m >= 1; m >>= 1) mx = fmaxf(mx, __shfl_xor(mx, m));
                float sum = 0.f;
                #pragma unroll
                for (int nt = 0; nt < 7; ++nt) { sv[nt] = __expf(sv[nt] - mx); sum += sv[nt]; }
                #pragma unroll
                for (int m = 8; m >= 1; m >>= 1) sum += __shfl_xor(sum, m);
                float inv = 1.0f / sum;
                int row = mt * 16 + g * 4 + j;
                #pragma unroll
                for (int nt = 0; nt < 7; ++nt)
                    P[row][nt * 16 + r] = f2bf(sv[nt] * inv);
            }
        }
    }
    __syncthreads();

    #pragma unroll
    for (int t = 0; t < 4; ++t) {
        int idx = wv + 4 * t;
        if (idx < 14) {
            int mt = idx >> 1, nt = idx & 1;
            int m0 = mt * 16, n0 = nt * 16;
            f32x4 acc = {0.f, 0.f, 0.f, 0.f};
            #pragma unroll
            for (int ks = 0; ks < 4; ++ks) {
                short8_t pa, vb;
                if (ks < 3 || g < 2) {
                    int k0 = ks * 32 + g * 8;
                    pa = *reinterpret_cast<const short8_t*>(&P[m0 + r][k0]);
                    vb = *reinterpret_cast<const short8_t*>(&vT[n0 + r][k0]);
                } else {
                    #pragma unroll
                    for (int j = 0; j < 8; ++j) { pa[j] = 0; vb[j] = 0; }
                }
                acc = __builtin_amdgcn_mfma_f32_16x16x32_bf16(pa, vb, acc, 0, 0, 0);
            }
            int d = n0 + r;
            int cl = head * 32 + d;
            float w9[9];
            #pragma unroll
            for (int j = 0; j < 9; ++j) w9[j] = cw[cl * 9 + j];
            float cbias = cb[cl];
            #pragma unroll
            for (int j = 0; j < 4; ++j) {
                int tok = m0 + g * 4 + j;
                float v = acc[j];
                int hs, wsp;
                if (type == 0) { hs = tok >> 1; wsp = tok & 1; }
                else           { hs = (tok >= 56) ? 1 : 0; wsp = tok - hs * 56; }
                float lp = cbias;
                #pragma unroll
                for (int ky = 0; ky < 3; ++ky) {
                    int hh = hs + ky - 1;
                    bool okh = (type == 0) ? (hh >= 0 && hh < 56) : (hh >= 0 && hh < 2);
                    #pragma unroll
                    for (int kx = 0; kx < 3; ++kx) {
                        int wwp = wsp + kx - 1;
                        bool okw = (type == 0) ? (wwp >= 0 && wwp < 2) : (wwp >= 0 && wwp < 56);
                        if (okh && okw) {
                            int tt = (type == 0) ? (hh * 2 + wwp) : (hh * 56 + wwp);
                            lp += w9[ky * 3 + kx] * bf2f(vT[d][tt]);
                        }
                    }
                }
                v += lp;
                int roww = rowof(tok);
                attout[(size_t)roww * 128 + chb + d] = f2bf(v);
            }
        }
    }
}

extern "C" void kernel_launch(void* const* d_in, const int* in_sizes, int n_in,
                              void* d_out, int out_size, void* d_ws, size_t ws_size,
                              hipStream_t stream) {
    const float* x      = (const float*)d_in[0];
    const float* n1g    = (const float*)d_in[1];
    const float* n1b    = (const float*)d_in[2];
    const float* qkv_w  = (const float*)d_in[3];
    const float* proj_w = (const float*)d_in[4];
    const float* proj_b = (const float*)d_in[5];
    const float* cw0    = (const float*)d_in[6];
    const float* cb0    = (const float*)d_in[7];
    const float* cw1    = (const float*)d_in[8];
    const float* cb1    = (const float*)d_in[9];
    const float* n2g    = (const float*)d_in[10];
    const float* n2b    = (const float*)d_in[11];
    const float* fc1_w  = (const float*)d_in[12];
    const float* fc1_b  = (const float*)d_in[13];
    const float* fc2_w  = (const float*)d_in[14];
    const float* fc2_b  = (const float*)d_in[15];
    float* out = (float*)d_out;
    char* ws = (char*)d_ws;

    short* img   = (short*)(ws + 0);            // [100352][128] bf16; later y2
    short* qkv   = (short*)(ws + 25690112);     // [100352][384] bf16
    short* att   = (short*)(ws + 102760448);    // [100352][128] bf16
    float* xres  = (float*)(ws + 128450560);    // [100352][128] f32
    short* wT    = (short*)(ws + 179830784);    // weights bf16 [N][K]
    short* wqkvT  = wT;
    short* wprojT = wT + 49152;
    short* wfc1T  = wT + 65536;
    short* wfc2T  = wT + 131072;
    short* y2     = img;

    prep_weights<<<768, 256, 0, stream>>>(qkv_w, proj_w, fc1_w, fc2_w, wT);
    ln_kernel<<<25088, 256, 0, stream>>>(x, n1g, n1b, img);
    gemm_qkv<<<dim3(6, 784), 256, 0, stream>>>(img, wqkvT, qkv);
    attn_kernel<<<dim3(896, 2, 2), 256, 0, stream>>>(qkv, cw0, cb0, cw1, cb1, att);
    gemm_proj<<<784, 256, 0, stream>>>(att, wprojT, proj_b, x, n2g, n2b, y2, xres);
    mlp_kernel<<<1568, 256, 0, stream>>>(y2, wfc1T, fc1_b, wfc2T, fc2_b, xres, out);
}

// Round 7
// 407.118 us; speedup vs baseline: 1.1347x; 1.0719x over previous
//
#include <hip/hip_runtime.h>
#include <hip/hip_bf16.h>
#include <math.h>

#define NTOK 100352          // 32*56*56
typedef __attribute__((ext_vector_type(8))) short short8_t;
typedef __attribute__((ext_vector_type(4))) float f32x4;

union I4S8 { int4 i; short h[8]; short8_t v; };

__device__ __forceinline__ short f2bf(float f) {
    union { float f; unsigned u; } x; x.f = f;
    unsigned r = x.u + 0x7FFFu + ((x.u >> 16) & 1u);
    return (short)(r >> 16);
}
__device__ __forceinline__ float bf2f(short s) {
    union { unsigned u; float f; } x; x.u = ((unsigned)(unsigned short)s) << 16;
    return x.f;
}
__device__ __forceinline__ unsigned pk2(float a, float b) {
    return ((unsigned)(unsigned short)f2bf(a)) | (((unsigned)(unsigned short)f2bf(b)) << 16);
}

// async global->LDS, 16B per lane, wave-uniform LDS base + lane*16
#define GLDS16(gsrc, ldst) __builtin_amdgcn_global_load_lds( \
    (const __attribute__((address_space(1))) unsigned int*)(gsrc), \
    (__attribute__((address_space(3))) unsigned int*)(ldst), 16, 0, 0)

// ---------------- weight prep: f32 [K][N] -> bf16 [N][K] ----------------
__global__ void prep_weights(const float* __restrict__ qkv_w, const float* __restrict__ proj_w,
                             const float* __restrict__ fc1_w, const float* __restrict__ fc2_w,
                             short* __restrict__ wt) {
    int idx = blockIdx.x * 256 + threadIdx.x;
    const float* src; int K, N, base;
    if (idx < 49152)       { src = qkv_w;  K = 128; N = 384; base = 0; }
    else if (idx < 65536)  { src = proj_w; K = 128; N = 128; base = 49152; }
    else if (idx < 131072) { src = fc1_w;  K = 128; N = 512; base = 65536; }
    else                   { src = fc2_w;  K = 512; N = 128; base = 131072; }
    int local = idx - base;
    int n = local / K, k = local - n * K;
    wt[idx] = f2bf(src[k * N + n]);
}

// ---------------- LayerNorm (f32 in) -> bf16 out ----------------
__global__ __launch_bounds__(256) void ln_kernel(const float* __restrict__ in,
                                                 const float* __restrict__ g,
                                                 const float* __restrict__ b,
                                                 short* __restrict__ out) {
    int token = blockIdx.x * 4 + (threadIdx.x >> 6);
    int lane = threadIdx.x & 63;
    const float2 v = *reinterpret_cast<const float2*>(in + (size_t)token * 128 + lane * 2);
    float s = v.x + v.y;
    float sq = v.x * v.x + v.y * v.y;
    #pragma unroll
    for (int m = 32; m >= 1; m >>= 1) {
        s  += __shfl_xor(s, m);
        sq += __shfl_xor(sq, m);
    }
    float mean = s * (1.0f / 128.0f);
    float var = sq * (1.0f / 128.0f) - mean * mean;
    float rstd = rsqrtf(var + 1e-5f);
    float2 gg = *reinterpret_cast<const float2*>(g + lane * 2);
    float2 bb = *reinterpret_cast<const float2*>(b + lane * 2);
    float o0 = (v.x - mean) * rstd * gg.x + bb.x;
    float o1 = (v.y - mean) * rstd * gg.y + bb.y;
    unsigned pack = ((unsigned)(unsigned short)f2bf(o0)) |
                    (((unsigned)(unsigned short)f2bf(o1)) << 16);
    *reinterpret_cast<unsigned*>(out + (size_t)token * 128 + lane * 2) = pack;
}

// ---------------- qkv: barrier-free streaming GEMM, M-loop + LDS dbuf ------------
// grid (392, 6). Each block: col-group c0=by*64, 4 M-steps (tile = bx + s*392) of
// 64 rows. Wave w stages AND reads only rows w*16..+15 -> NO cross-wave LDS deps,
// NO barriers. Pipeline: waitcnt(0) [stage(s) ready] -> ds_read -> issue stage(s+1)
// -> MFMA -> store. Weights (64 cols x K128) in registers, loaded once.
__global__ __launch_bounds__(256) void gemm_qkv(const short* __restrict__ A,
                                                const short* __restrict__ WT,
                                                short* __restrict__ outb) {
    __shared__ short As[2][64 * 128];   // 2 x 16 KB
    const int tid = threadIdx.x;
    const int w = tid >> 6, lane = tid & 63;
    const int r = lane & 15, g = lane >> 4;
    const int ri = lane >> 4, sl = lane & 15;     // staging: row-in-4-group, 16B slot
    const int c0 = blockIdx.y * 64;

    // weight panel: 64 cols x K=128 -> 64 VGPR, loaded once (L2-hot)
    short8_t bfr[4][4];
    #pragma unroll
    for (int nt = 0; nt < 4; ++nt)
        #pragma unroll
        for (int kf = 0; kf < 4; ++kf)
            bfr[nt][kf] = *reinterpret_cast<const short8_t*>(
                WT + (size_t)(c0 + nt * 16 + r) * 128 + kf * 32 + g * 8);

    int tile = blockIdx.x;
    // prologue: stage tile 0 into buf 0 (wave w -> rows w*16..+15)
    {
        const short* base = A + (size_t)tile * 64 * 128;
        #pragma unroll
        for (int t = 0; t < 4; ++t) {
            int row = w * 16 + t * 4 + ri;
            int ss = (sl & 8) | ((sl ^ row) & 7);
            GLDS16(base + row * 128 + ss * 8, &As[0][(w * 16 + t * 4) * 128]);
        }
    }
    int cur = 0;
    #pragma unroll
    for (int s = 0; s < 4; ++s) {
        asm volatile("s_waitcnt vmcnt(0)" ::: "memory");
        __builtin_amdgcn_sched_barrier(0);
        // A frags for this wave's 16 rows
        short8_t af[4];
        #pragma unroll
        for (int kf = 0; kf < 4; ++kf) {
            int row = w * 16 + r;
            int q = kf * 4 + g;
            int ss = (q & 8) | ((q ^ row) & 7);
            af[kf] = *reinterpret_cast<const short8_t*>(&As[cur][row * 128 + ss * 8]);
        }
        // issue next stage early: overlaps MFMA + stores below
        if (s + 1 < 4) {
            const short* base = A + (size_t)(tile + 392) * 64 * 128;
            #pragma unroll
            for (int t = 0; t < 4; ++t) {
                int row = w * 16 + t * 4 + ri;
                int ss = (sl & 8) | ((sl ^ row) & 7);
                GLDS16(base + row * 128 + ss * 8, &As[cur ^ 1][(w * 16 + t * 4) * 128]);
            }
        }
        f32x4 acc[4];
        #pragma unroll
        for (int nt = 0; nt < 4; ++nt) acc[nt] = (f32x4){0.f, 0.f, 0.f, 0.f};
        #pragma unroll
        for (int kf = 0; kf < 4; ++kf)
            #pragma unroll
            for (int nt = 0; nt < 4; ++nt)
                acc[nt] = __builtin_amdgcn_mfma_f32_16x16x32_bf16(bfr[nt][kf], af[kf], acc[nt], 0, 0, 0);
        int row = tile * 64 + w * 16 + r;
        #pragma unroll
        for (int nt = 0; nt < 4; ++nt) {
            int col = c0 + nt * 16 + g * 4;
            uint2 p;
            p.x = pk2(acc[nt][0], acc[nt][1]);
            p.y = pk2(acc[nt][2], acc[nt][3]);
            *reinterpret_cast<uint2*>(&outb[(size_t)row * 384 + col]) = p;
        }
        cur ^= 1; tile += 392;
    }
}

// ---------------- proj + bias + residual + LN2: same barrier-free streaming ------
// grid (784). 2 M-steps of 64 rows. Wave owns 16 rows x all 128 cols (LN needs full
// rows). Weights 128 cols x K128 in regs (128 VGPR).
__global__ __launch_bounds__(256) void gemm_proj(const short* __restrict__ A,
                                                 const short* __restrict__ WT,
                                                 const float* __restrict__ bias,
                                                 const float* __restrict__ resid,
                                                 const float* __restrict__ g2,
                                                 const float* __restrict__ b2,
                                                 short* __restrict__ y2,
                                                 float* __restrict__ xres) {
    __shared__ short As[2][64 * 128];   // 2 x 16 KB
    const int tid = threadIdx.x;
    const int w = tid >> 6, lane = tid & 63;
    const int r = lane & 15, g = lane >> 4;
    const int ri = lane >> 4, sl = lane & 15;

    short8_t bfr[8][4];
    #pragma unroll
    for (int nt = 0; nt < 8; ++nt)
        #pragma unroll
        for (int kf = 0; kf < 4; ++kf)
            bfr[nt][kf] = *reinterpret_cast<const short8_t*>(
                WT + (size_t)(nt * 16 + r) * 128 + kf * 32 + g * 8);

    int tile = blockIdx.x;
    {
        const short* base = A + (size_t)tile * 64 * 128;
        #pragma unroll
        for (int t = 0; t < 4; ++t) {
            int row = w * 16 + t * 4 + ri;
            int ss = (sl & 8) | ((sl ^ row) & 7);
            GLDS16(base + row * 128 + ss * 8, &As[0][(w * 16 + t * 4) * 128]);
        }
    }
    int cur = 0;
    #pragma unroll
    for (int s = 0; s < 2; ++s) {
        asm volatile("s_waitcnt vmcnt(0)" ::: "memory");
        __builtin_amdgcn_sched_barrier(0);
        short8_t af[4];
        #pragma unroll
        for (int kf = 0; kf < 4; ++kf) {
            int row = w * 16 + r;
            int q = kf * 4 + g;
            int ss = (q & 8) | ((q ^ row) & 7);
            af[kf] = *reinterpret_cast<const short8_t*>(&As[cur][row * 128 + ss * 8]);
        }
        if (s + 1 < 2) {
            const short* base = A + (size_t)(tile + 784) * 64 * 128;
            #pragma unroll
            for (int t = 0; t < 4; ++t) {
                int row = w * 16 + t * 4 + ri;
                int ss = (sl & 8) | ((sl ^ row) & 7);
                GLDS16(base + row * 128 + ss * 8, &As[cur ^ 1][(w * 16 + t * 4) * 128]);
            }
        }
        f32x4 acc[8];
        #pragma unroll
        for (int nt = 0; nt < 8; ++nt) acc[nt] = (f32x4){0.f, 0.f, 0.f, 0.f};
        #pragma unroll
        for (int kf = 0; kf < 4; ++kf)
            #pragma unroll
            for (int nt = 0; nt < 8; ++nt)
                acc[nt] = __builtin_amdgcn_mfma_f32_16x16x32_bf16(bfr[nt][kf], af[kf], acc[nt], 0, 0, 0);

        int row = tile * 64 + w * 16 + r;
        float sm = 0.f, sq = 0.f;
        #pragma unroll
        for (int nt = 0; nt < 8; ++nt) {
            int col = nt * 16 + g * 4;
            f32x4 b4 = *reinterpret_cast<const f32x4*>(&bias[col]);
            f32x4 x4 = *reinterpret_cast<const f32x4*>(&resid[(size_t)row * 128 + col]);
            #pragma unroll
            for (int j = 0; j < 4; ++j) {
                float v = acc[nt][j] + b4[j] + x4[j];
                acc[nt][j] = v;
                sm += v; sq += v * v;
            }
            *reinterpret_cast<f32x4*>(&xres[(size_t)row * 128 + col]) = acc[nt];
        }
        sm += __shfl_xor(sm, 16); sm += __shfl_xor(sm, 32);
        sq += __shfl_xor(sq, 16); sq += __shfl_xor(sq, 32);
        float mean = sm * (1.0f / 128.0f);
        float var = sq * (1.0f / 128.0f) - mean * mean;
        float rstd = rsqrtf(var + 1e-5f);
        #pragma unroll
        for (int nt = 0; nt < 8; ++nt) {
            int col = nt * 16 + g * 4;
            f32x4 g4  = *reinterpret_cast<const f32x4*>(&g2[col]);
            f32x4 bb4 = *reinterpret_cast<const f32x4*>(&b2[col]);
            uint2 p;
            p.x = pk2((acc[nt][0] - mean) * rstd * g4[0] + bb4[0],
                      (acc[nt][1] - mean) * rstd * g4[1] + bb4[1]);
            p.y = pk2((acc[nt][2] - mean) * rstd * g4[2] + bb4[2],
                      (acc[nt][3] - mean) * rstd * g4[3] + bb4[3]);
            *reinterpret_cast<uint2*>(&y2[(size_t)row * 128 + col]) = p;
        }
        cur ^= 1; tile += 784;
    }
}

// ---------------- fused MLP: fc1 + GELU(erff) + fc2 + bias + residual --------------
// exact round-4 structure (measured 125 us)
__global__ __launch_bounds__(256) void mlp_kernel(const short* __restrict__ Y,
                                                  const short* __restrict__ W1T,   // [512][128]
                                                  const float* __restrict__ b1,
                                                  const short* __restrict__ W2T,   // [128][512]
                                                  const float* __restrict__ b2,
                                                  const float* __restrict__ xres,
                                                  float* __restrict__ out) {
    __shared__ short hid[64 * 512];   // 64 KB
    const int m0 = blockIdx.x * 64;
    const int tid = threadIdx.x;
    const int w = tid >> 6, lane = tid & 63;
    const int r = lane & 15, g = lane >> 4;

    short8_t af[4][4];
    #pragma unroll
    for (int mf = 0; mf < 4; ++mf)
        #pragma unroll
        for (int kf = 0; kf < 4; ++kf)
            af[mf][kf] = *reinterpret_cast<const short8_t*>(
                &Y[(size_t)(m0 + mf * 16 + r) * 128 + kf * 32 + g * 8]);

    #pragma unroll
    for (int np = 0; np < 2; ++np) {
        f32x4 acc[4][4];
        #pragma unroll
        for (int mf = 0; mf < 4; ++mf)
            #pragma unroll
            for (int nt = 0; nt < 4; ++nt) acc[mf][nt] = (f32x4){0.f, 0.f, 0.f, 0.f};
        #pragma unroll
        for (int kf = 0; kf < 4; ++kf) {
            short8_t bfr[4];
            #pragma unroll
            for (int nt = 0; nt < 4; ++nt) {
                int hc = w * 128 + np * 64 + nt * 16 + r;
                bfr[nt] = *reinterpret_cast<const short8_t*>(&W1T[(size_t)hc * 128 + kf * 32 + g * 8]);
            }
            #pragma unroll
            for (int mf = 0; mf < 4; ++mf)
                #pragma unroll
                for (int nt = 0; nt < 4; ++nt)
                    acc[mf][nt] = __builtin_amdgcn_mfma_f32_16x16x32_bf16(bfr[nt], af[mf][kf], acc[mf][nt], 0, 0, 0);
        }
        #pragma unroll
        for (int mf = 0; mf < 4; ++mf) {
            int row = mf * 16 + r;
            #pragma unroll
            for (int nt = 0; nt < 4; ++nt) {
                int col = w * 128 + np * 64 + nt * 16 + g * 4;
                f32x4 b4 = *reinterpret_cast<const f32x4*>(&b1[col]);
                float h[4];
                #pragma unroll
                for (int j = 0; j < 4; ++j) {
                    float t = acc[mf][nt][j] + b4[j];
                    h[j] = 0.5f * t * (1.0f + erff(t * 0.70710678118654752f));
                }
                int s16 = col >> 3;
                int half = (col >> 2) & 1;
                int seg = (s16 & 56) | ((s16 ^ row) & 7);
                uint2 p; p.x = pk2(h[0], h[1]); p.y = pk2(h[2], h[3]);
                *reinterpret_cast<uint2*>((char*)hid + row * 1024 + seg * 16 + half * 8) = p;
            }
        }
    }
    __syncthreads();

    f32x4 acc2[4][2];
    #pragma unroll
    for (int tt = 0; tt < 4; ++tt)
        #pragma unroll
        for (int o = 0; o < 2; ++o) acc2[tt][o] = (f32x4){0.f, 0.f, 0.f, 0.f};
    #pragma unroll
    for (int kf = 0; kf < 16; ++kf) {
        const int q = kf * 4 + g;
        short8_t bf2[2], hf[4];
        #pragma unroll
        for (int o = 0; o < 2; ++o) {
            int ocol = w * 32 + o * 16 + r;
            bf2[o] = *reinterpret_cast<const short8_t*>(&W2T[(size_t)ocol * 512 + kf * 32 + g * 8]);
        }
        #pragma unroll
        for (int tt = 0; tt < 4; ++tt) {
            int row = tt * 16 + r;
            int seg = (q & 56) | ((q ^ row) & 7);
            hf[tt] = *reinterpret_cast<const short8_t*>((char*)hid + row * 1024 + seg * 16);
        }
        #pragma unroll
        for (int tt = 0; tt < 4; ++tt)
            #pragma unroll
            for (int o = 0; o < 2; ++o)
                acc2[tt][o] = __builtin_amdgcn_mfma_f32_16x16x32_bf16(bf2[o], hf[tt], acc2[tt][o], 0, 0, 0);
    }
    #pragma unroll
    for (int tt = 0; tt < 4; ++tt) {
        int row = m0 + tt * 16 + r;
        #pragma unroll
        for (int o = 0; o < 2; ++o) {
            int col = w * 32 + o * 16 + g * 4;
            f32x4 b4 = *reinterpret_cast<const f32x4*>(&b2[col]);
            f32x4 x4 = *reinterpret_cast<const f32x4*>(&xres[(size_t)row * 128 + col]);
            f32x4 v;
            #pragma unroll
            for (int j = 0; j < 4; ++j) v[j] = acc2[tt][o][j] + b4[j] + x4[j];
            *reinterpret_cast<f32x4*>(&out[(size_t)row * 128 + col]) = v;
        }
    }
}

// ---------------- fused window attention + LEPE (wave-parallel softmax) ----------------
__global__ __launch_bounds__(256) void attn_kernel(const short* __restrict__ qkv,
                                                   const float* __restrict__ cw0,
                                                   const float* __restrict__ cb0,
                                                   const float* __restrict__ cw1,
                                                   const float* __restrict__ cb1,
                                                   short* __restrict__ attout) {
    __shared__ short P[112][120];   // normalized probs, bf16
    __shared__ short vT[32][120];   // V transposed: vT[d][tok]

    const int win = blockIdx.x;
    const int head = blockIdx.y;
    const int type = blockIdx.z;
    const int b = win / 28;
    const int wdx = win - b * 28;
    const int tid = threadIdx.x;
    const int wv = tid >> 6, lane = tid & 63;
    const int r = lane & 15, g = lane >> 4;
    const int chb = type * 64 + head * 32;
    const float* cw = type ? cw1 : cw0;
    const float* cb = type ? cb1 : cb0;

    auto rowof = [&](int t) -> int {
        int l;
        if (type == 0) { int hs = t >> 1, wsp = t & 1; l = hs * 56 + wdx * 2 + wsp; }
        else           { int hs = (t >= 56) ? 1 : 0, wsp = t - hs * 56; l = (wdx * 2 + hs) * 56 + wsp; }
        return b * 3136 + l;
    };

    for (int i = tid; i < 448; i += 256) {
        int tt = i >> 2, seg = i & 3;
        int roww = rowof(tt);
        I4S8 u; u.i = *reinterpret_cast<const int4*>(qkv + (size_t)roww * 384 + 256 + chb + seg * 8);
        #pragma unroll
        for (int j = 0; j < 8; ++j) vT[seg * 8 + j][tt] = u.h[j];
    }

    short8_t kf[7];
    #pragma unroll
    for (int nt = 0; nt < 7; ++nt) {
        int roww = rowof(nt * 16 + r);
        kf[nt] = *reinterpret_cast<const short8_t*>(qkv + (size_t)roww * 384 + 128 + chb + g * 8);
    }

    f32x4 sa[2][7];
    #pragma unroll
    for (int t = 0; t < 2; ++t)
        #pragma unroll
        for (int nt = 0; nt < 7; ++nt)
            sa[t][nt] = (f32x4){0.f, 0.f, 0.f, 0.f};

    #pragma unroll
    for (int t = 0; t < 2; ++t) {
        int mt = wv + 4 * t;
        if (mt < 7) {
            int roww = rowof(mt * 16 + r);
            short8_t af = *reinterpret_cast<const short8_t*>(qkv + (size_t)roww * 384 + chb + g * 8);
            #pragma unroll
            for (int nt = 0; nt < 7; ++nt)
                sa[t][nt] = __builtin_amdgcn_mfma_f32_16x16x32_bf16(af, kf[nt], sa[t][nt], 0, 0, 0);
        }
    }

    const float scale = 0.17677669529663687f; // 1/sqrt(32)
    #pragma unroll
    for (int t = 0; t < 2; ++t) {
        int mt = wv + 4 * t;
        if (mt < 7) {
            #pragma unroll
            for (int j = 0; j < 4; ++j) {
                float sv[7];
                float mx = -1e30f;
                #pragma unroll
                for (int nt = 0; nt < 7; ++nt) { sv[nt] = sa[t][nt][j] * scale; mx = fmaxf(mx, sv[nt]); }
                #pragma unroll
                for (int m = 8; m >= 1; m >>= 1) mx = fmaxf(mx, __shfl_xor(mx, m));
                float sum = 0.f;
                #pragma unroll
                for (int nt = 0; nt < 7; ++nt) { sv[nt] = __expf(sv[nt] - mx); sum += sv[nt]; }
                #pragma unroll
                for (int m = 8; m >= 1; m >>= 1) sum += __shfl_xor(sum, m);
                float inv = 1.0f / sum;
                int row = mt * 16 + g * 4 + j;
                #pragma unroll
                for (int nt = 0; nt < 7; ++nt)
                    P[row][nt * 16 + r] = f2bf(sv[nt] * inv);
            }
        }
    }
    __syncthreads();

    #pragma unroll
    for (int t = 0; t < 4; ++t) {
        int idx = wv + 4 * t;
        if (idx < 14) {
            int mt = idx >> 1, nt = idx & 1;
            int m0 = mt * 16, n0 = nt * 16;
            f32x4 acc = {0.f, 0.f, 0.f, 0.f};
            #pragma unroll
            for (int ks = 0; ks < 4; ++ks) {
                short8_t pa, vb;
                if (ks < 3 || g < 2) {
                    int k0 = ks * 32 + g * 8;
                    pa = *reinterpret_cast<const short8_t*>(&P[m0 + r][k0]);
                    vb = *reinterpret_cast<const short8_t*>(&vT[n0 + r][k0]);
                } else {
                    #pragma unroll
                    for (int j = 0; j < 8; ++j) { pa[j] = 0; vb[j] = 0; }
                }
                acc = __builtin_amdgcn_mfma_f32_16x16x32_bf16(pa, vb, acc, 0, 0, 0);
            }
            int d = n0 + r;
            int cl = head * 32 + d;
            float w9[9];
            #pragma unroll
            for (int j = 0; j < 9; ++j) w9[j] = cw[cl * 9 + j];
            float cbias = cb[cl];
            #pragma unroll
            for (int j = 0; j < 4; ++j) {
                int tok = m0 + g * 4 + j;
                float v = acc[j];
                int hs, wsp;
                if (type == 0) { hs = tok >> 1; wsp = tok & 1; }
                else           { hs = (tok >= 56) ? 1 : 0; wsp = tok - hs * 56; }
                float lp = cbias;
                #pragma unroll
                for (int ky = 0; ky < 3; ++ky) {
                    int hh = hs + ky - 1;
                    bool okh = (type == 0) ? (hh >= 0 && hh < 56) : (hh >= 0 && hh < 2);
                    #pragma unroll
                    for (int kx = 0; kx < 3; ++kx) {
                        int wwp = wsp + kx - 1;
                        bool okw = (type == 0) ? (wwp >= 0 && wwp < 2) : (wwp >= 0 && wwp < 56);
                        if (okh && okw) {
                            int tt = (type == 0) ? (hh * 2 + wwp) : (hh * 56 + wwp);
                            lp += w9[ky * 3 + kx] * bf2f(vT[d][tt]);
                        }
                    }
                }
                v += lp;
                int roww = rowof(tok);
                attout[(size_t)roww * 128 + chb + d] = f2bf(v);
            }
        }
    }
}

extern "C" void kernel_launch(void* const* d_in, const int* in_sizes, int n_in,
                              void* d_out, int out_size, void* d_ws, size_t ws_size,
                              hipStream_t stream) {
    const float* x      = (const float*)d_in[0];
    const float* n1g    = (const float*)d_in[1];
    const float* n1b    = (const float*)d_in[2];
    const float* qkv_w  = (const float*)d_in[3];
    const float* proj_w = (const float*)d_in[4];
    const float* proj_b = (const float*)d_in[5];
    const float* cw0    = (const float*)d_in[6];
    const float* cb0    = (const float*)d_in[7];
    const float* cw1    = (const float*)d_in[8];
    const float* cb1    = (const float*)d_in[9];
    const float* n2g    = (const float*)d_in[10];
    const float* n2b    = (const float*)d_in[11];
    const float* fc1_w  = (const float*)d_in[12];
    const float* fc1_b  = (const float*)d_in[13];
    const float* fc2_w  = (const float*)d_in[14];
    const float* fc2_b  = (const float*)d_in[15];
    float* out = (float*)d_out;
    char* ws = (char*)d_ws;

    short* img   = (short*)(ws + 0);            // [100352][128] bf16; later y2
    short* qkv   = (short*)(ws + 25690112);     // [100352][384] bf16
    short* att   = (short*)(ws + 102760448);    // [100352][128] bf16
    float* xres  = (float*)(ws + 128450560);    // [100352][128] f32
    short* wT    = (short*)(ws + 179830784);    // weights bf16 [N][K]
    short* wqkvT  = wT;
    short* wprojT = wT + 49152;
    short* wfc1T  = wT + 65536;
    short* wfc2T  = wT + 131072;
    short* y2     = img;

    prep_weights<<<768, 256, 0, stream>>>(qkv_w, proj_w, fc1_w, fc2_w, wT);
    ln_kernel<<<25088, 256, 0, stream>>>(x, n1g, n1b, img);
    gemm_qkv<<<dim3(392, 6), 256, 0, stream>>>(img, wqkvT, qkv);
    attn_kernel<<<dim3(896, 2, 2), 256, 0, stream>>>(qkv, cw0, cb0, cw1, cb1, att);
    gemm_proj<<<784, 256, 0, stream>>>(att, wprojT, proj_b, x, n2g, n2b, y2, xres);
    mlp_kernel<<<1568, 256, 0, stream>>>(y2, wfc1T, fc1_b, wfc2T, fc2_b, xres, out);
}